// Round 2
// baseline (1045.559 us; speedup 1.0000x reference)
//
#include <hip/hip_runtime.h>
#include <stdint.h>

#define NN 100000
#define NE 1600000
#define NG 64
#define DIN 128
#define HID 256
#define NATTR 8

__device__ __forceinline__ int imaxi(int a, int b) { return a > b ? a : b; }

// ---------------- zero fill ----------------

__global__ void k_zero(int* __restrict__ p, int n) {
    int i = blockIdx.x * 256 + threadIdx.x;
    if (i < n) p[i] = 0;
}

// ---------------- CSR build ----------------

__global__ void k_count(const int* __restrict__ ei, int* __restrict__ deg) {
    int e = blockIdx.x * 256 + threadIdx.x;
    if (e < NE) atomicAdd(&deg[ei[NE + e]], 1);
}

__global__ void k_scan_part(const int* __restrict__ deg, int* __restrict__ part) {
    __shared__ int red[256];
    int t = threadIdx.x;
    int base = blockIdx.x * 1024 + t * 4;
    int s = 0;
#pragma unroll
    for (int j = 0; j < 4; j++) { int i = base + j; s += (i < NN) ? deg[i] : 0; }
    red[t] = s; __syncthreads();
    for (int off = 128; off > 0; off >>= 1) {
        if (t < off) red[t] += red[t + off];
        __syncthreads();
    }
    if (t == 0) part[blockIdx.x] = red[0];
}

__global__ void k_scan_top(const int* __restrict__ part, int* __restrict__ poff, int nchunks) {
    if (threadIdx.x == 0) {
        int run = 0;
        for (int i = 0; i < nchunks; i++) { poff[i] = run; run += part[i]; }
    }
}

__global__ void k_scan_final(const int* __restrict__ deg, const int* __restrict__ poff,
                             int* __restrict__ rowptr, int* __restrict__ cursor) {
    __shared__ int arr[256];
    int t = threadIdx.x;
    int base = blockIdx.x * 1024 + t * 4;
    int v[4];
#pragma unroll
    for (int j = 0; j < 4; j++) { int i = base + j; v[j] = (i < NN) ? deg[i] : 0; }
    int T = v[0] + v[1] + v[2] + v[3];
    arr[t] = T; __syncthreads();
    for (int off = 1; off < 256; off <<= 1) {
        int add = (t >= off) ? arr[t - off] : 0;
        __syncthreads();
        arr[t] += add;
        __syncthreads();
    }
    int ex = poff[blockIdx.x] + arr[t] - T;
    int pre = 0;
#pragma unroll
    for (int j = 0; j < 4; j++) {
        int i = base + j;
        int val = ex + pre;
        if (i <= NN) rowptr[i] = val;
        if (i < NN) cursor[i] = val;
        pre += v[j];
    }
}

__global__ void k_fill(const int* __restrict__ ei, int* __restrict__ cursor, int* __restrict__ col) {
    int e = blockIdx.x * 256 + threadIdx.x;
    if (e < NE) {
        int d = ei[NE + e];
        int p = atomicAdd(&cursor[d], 1);
        col[p] = ei[e];
    }
}

// ---------------- mean aggregation for layer 1 (CSR gather, D=128) ----------------
// one wave per node; lane handles 2 floats (float2)

__global__ void k_agg128(const float* __restrict__ X, float* __restrict__ O,
                         const int* __restrict__ rowptr, const int* __restrict__ col) {
    int node = blockIdx.x * 4 + (threadIdx.x >> 6);
    int lane = threadIdx.x & 63;
    if (node >= NN) return;
    int s = rowptr[node], e = rowptr[node + 1];
    float ax = 0.f, ay = 0.f;
    const float2* Xv = (const float2*)X;  // DIN/2 = 64 per row
    for (int i = s; i < e; i++) {
        int u = col[i];
        float2 w = Xv[(size_t)u * (DIN / 2) + lane];
        ax += w.x; ay += w.y;
    }
    float inv = 1.f / (float)imaxi(e - s, 1);
    float2 o; o.x = ax * inv; o.y = ay * inv;
    ((float2*)O)[(size_t)node * (DIN / 2) + lane] = o;
}

// ---------------- fused two-phase GEMM: h1 = relu(agg1@W1l + x@W1r + b1) ----------------
// 64x64 tile, 4x4 per thread, fp32.

__global__ void k_gemm(const float* __restrict__ A0, const float* __restrict__ B0,
                       const float* __restrict__ A1, const float* __restrict__ B1,
                       const float* __restrict__ bias, float* __restrict__ C) {
    __shared__ float As[16][65];
    __shared__ float Bs[16][65];
    int t = threadIdx.x;
    int m0 = blockIdx.x * 64;
    int n0 = blockIdx.y * 64;
    int tm = t >> 4, tn = t & 15;
    int arow = t >> 2, ac4 = (t & 3) * 4;
    int brow = t >> 4, bc4 = (t & 15) * 4;
    float acc[4][4] = {};
    const float* A = A0;
    const float* B = B0;
#pragma unroll
    for (int ph = 0; ph < 2; ph++) {
        for (int k0 = 0; k0 < DIN; k0 += 16) {
            int m = m0 + arow;
            float4 av = {0.f, 0.f, 0.f, 0.f};
            if (m < NN) av = *(const float4*)(A + (size_t)m * DIN + k0 + ac4);
            As[ac4 + 0][arow] = av.x;
            As[ac4 + 1][arow] = av.y;
            As[ac4 + 2][arow] = av.z;
            As[ac4 + 3][arow] = av.w;
            float4 bv = *(const float4*)(B + (size_t)(k0 + brow) * HID + n0 + bc4);
            Bs[brow][bc4 + 0] = bv.x;
            Bs[brow][bc4 + 1] = bv.y;
            Bs[brow][bc4 + 2] = bv.z;
            Bs[brow][bc4 + 3] = bv.w;
            __syncthreads();
#pragma unroll
            for (int k = 0; k < 16; k++) {
                float ar[4], br[4];
#pragma unroll
                for (int i = 0; i < 4; i++) ar[i] = As[k][tm * 4 + i];
#pragma unroll
                for (int j = 0; j < 4; j++) br[j] = Bs[k][tn * 4 + j];
#pragma unroll
                for (int i = 0; i < 4; i++)
#pragma unroll
                    for (int j = 0; j < 4; j++) acc[i][j] += ar[i] * br[j];
            }
            __syncthreads();
        }
        A = A1; B = B1;
    }
    float bv4[4];
#pragma unroll
    for (int j = 0; j < 4; j++) bv4[j] = bias[n0 + tn * 4 + j];
#pragma unroll
    for (int i = 0; i < 4; i++) {
        int m = m0 + tm * 4 + i;
        if (m < NN) {
            float4 o;
            o.x = fmaxf(acc[i][0] + bv4[0], 0.f);
            o.y = fmaxf(acc[i][1] + bv4[1], 0.f);
            o.z = fmaxf(acc[i][2] + bv4[2], 0.f);
            o.w = fmaxf(acc[i][3] + bv4[3], 0.f);
            *(float4*)(C + (size_t)m * HID + n0 + tn * 4) = o;
        }
    }
}

// ---------------- layer-2 pooled scatter ----------------
// PA[g] = sum_{v in g} (1/max(deg_v,1)) * sum_{u in N(v)} h1[u]
// PH[g] = sum_{v in g} h1[v]
// One wave handles 16 consecutive nodes (batch sorted -> few graph changes);
// register run-length accumulation, atomic flush on graph change.

__global__ void k_pool(const float* __restrict__ h1, const int* __restrict__ rowptr,
                       const int* __restrict__ col, const int* __restrict__ batch,
                       float* __restrict__ PA, float* __restrict__ PH) {
    int wave = blockIdx.x * 4 + (threadIdx.x >> 6);
    int lane = threadIdx.x & 63;
    int n0 = wave * 16;
    if (n0 >= NN) return;
    int nend = n0 + 16; if (nend > NN) nend = NN;
    const float4* H = (const float4*)h1;  // HID/4 = 64 per row
    float aA0 = 0, aA1 = 0, aA2 = 0, aA3 = 0;
    float aH0 = 0, aH1 = 0, aH2 = 0, aH3 = 0;
    int cg = -1;
    for (int v = n0; v < nend; v++) {
        int g = batch[v];
        if (g != cg) {
            if (cg >= 0) {
                float* pa = &PA[cg * HID + lane * 4];
                float* ph = &PH[cg * HID + lane * 4];
                atomicAdd(pa + 0, aA0); atomicAdd(pa + 1, aA1);
                atomicAdd(pa + 2, aA2); atomicAdd(pa + 3, aA3);
                atomicAdd(ph + 0, aH0); atomicAdd(ph + 1, aH1);
                atomicAdd(ph + 2, aH2); atomicAdd(ph + 3, aH3);
                aA0 = aA1 = aA2 = aA3 = 0;
                aH0 = aH1 = aH2 = aH3 = 0;
            }
            cg = g;
        }
        int s = rowptr[v], e = rowptr[v + 1];
        float s0 = 0, s1 = 0, s2 = 0, s3 = 0;
        for (int i = s; i < e; i++) {
            int u = col[i];
            float4 w = H[(size_t)u * (HID / 4) + lane];
            s0 += w.x; s1 += w.y; s2 += w.z; s3 += w.w;
        }
        float inv = 1.f / (float)imaxi(e - s, 1);
        aA0 += s0 * inv; aA1 += s1 * inv; aA2 += s2 * inv; aA3 += s3 * inv;
        float4 hv = H[(size_t)v * (HID / 4) + lane];
        aH0 += hv.x; aH1 += hv.y; aH2 += hv.z; aH3 += hv.w;
    }
    if (cg >= 0) {
        float* pa = &PA[cg * HID + lane * 4];
        float* ph = &PH[cg * HID + lane * 4];
        atomicAdd(pa + 0, aA0); atomicAdd(pa + 1, aA1);
        atomicAdd(pa + 2, aA2); atomicAdd(pa + 3, aA3);
        atomicAdd(ph + 0, aH0); atomicAdd(ph + 1, aH1);
        atomicAdd(ph + 2, aH2); atomicAdd(ph + 3, aH3);
    }
}

// ---------------- per-graph node counts ----------------

__global__ void k_gcnt(const int* __restrict__ batch, int* __restrict__ gcnt) {
    __shared__ int lc[NG];
    int t = threadIdx.x;
    if (t < NG) lc[t] = 0;
    __syncthreads();
    int n = blockIdx.x * 256 + t;
    if (n < NN) atomicAdd(&lc[batch[n]], 1);
    __syncthreads();
    if (t < NG && lc[t] > 0) atomicAdd(&gcnt[t], lc[t]);
}

// ---------------- head: layer-2 pooled output + final MLP ----------------
// g = (PA@W2l + PH@W2r)/cnt + b2 ; out = relu([g, attr]@Wf1 + bf1)@Wf2 + bf2

__global__ void k_head(const float* __restrict__ PA, const float* __restrict__ PH,
                       const int* __restrict__ gcnt, const float* __restrict__ gattr,
                       const float* __restrict__ W2l, const float* __restrict__ b2,
                       const float* __restrict__ W2r,
                       const float* __restrict__ Wf1, const float* __restrict__ bf1,
                       const float* __restrict__ Wf2, const float* __restrict__ bf2v,
                       float* __restrict__ out) {
    __shared__ float pa[HID], ph[HID], gv[HID + NATTR];
    __shared__ float red[256];
    int g = blockIdx.x, t = threadIdx.x;
    pa[t] = PA[g * HID + t];
    ph[t] = PH[g * HID + t];
    __syncthreads();
    float s = 0.f;
    for (int k = 0; k < HID; k++)
        s += pa[k] * W2l[k * HID + t] + ph[k] * W2r[k * HID + t];
    float invc = 1.f / (float)imaxi(gcnt[g], 1);
    gv[t] = s * invc + b2[t];
    if (t < NATTR) gv[HID + t] = gattr[g * NATTR + t];
    __syncthreads();
    float h = bf1[t];
    for (int k = 0; k < HID + NATTR; k++) h += gv[k] * Wf1[k * HID + t];
    h = fmaxf(h, 0.f);
    red[t] = h * Wf2[t];
    __syncthreads();
    for (int off = 128; off > 0; off >>= 1) {
        if (t < off) red[t] += red[t + off];
        __syncthreads();
    }
    if (t == 0) out[g] = red[0] + bf2v[0];
}

// ---------------- launch ----------------

extern "C" void kernel_launch(void* const* d_in, const int* in_sizes, int n_in,
                              void* d_out, int out_size, void* d_ws, size_t ws_size,
                              hipStream_t stream) {
    (void)in_sizes; (void)n_in; (void)out_size; (void)ws_size;
    const float* x     = (const float*)d_in[0];
    const int*   ei    = (const int*)d_in[1];
    const int*   batch = (const int*)d_in[2];
    const float* gattr = (const float*)d_in[3];
    const float* W1l   = (const float*)d_in[4];
    const float* b1    = (const float*)d_in[5];
    const float* W1r   = (const float*)d_in[6];
    const float* W2l   = (const float*)d_in[7];
    const float* b2    = (const float*)d_in[8];
    const float* W2r   = (const float*)d_in[9];
    const float* Wf1   = (const float*)d_in[10];
    const float* bf1   = (const float*)d_in[11];
    const float* Wf2   = (const float*)d_in[12];
    const float* bf2v  = (const float*)d_in[13];
    float* out = (float*)d_out;

    uint8_t* w = (uint8_t*)d_ws;
    size_t off = 0;
    auto alloc = [&](size_t bytes) -> void* {
        void* p = w + off;
        off += (bytes + 255) & ~(size_t)255;
        return p;
    };
    float* agg1   = (float*)alloc((size_t)NN * DIN * 4);   // 51.2 MB
    float* h1     = (float*)alloc((size_t)NN * HID * 4);   // 102.4 MB
    int*   deg    = (int*)alloc((size_t)NN * 4);
    int*   rowptr = (int*)alloc((size_t)(NN + 1) * 4);
    int*   cursor = (int*)alloc((size_t)NN * 4);
    int*   col    = (int*)alloc((size_t)NE * 4);           // 6.4 MB
    int*   part   = (int*)alloc(128 * 4);
    int*   poff   = (int*)alloc(128 * 4);
    float* PA     = (float*)alloc((size_t)NG * HID * 4);   // contiguous with PH, gcnt
    float* PH     = (float*)alloc((size_t)NG * HID * 4);
    int*   gcnt   = (int*)alloc(NG * 4);

    const int nchunks = (NN + 1023) / 1024;  // 98

    k_zero<<<(NN + 255) / 256, 256, 0, stream>>>(deg, NN);
    k_zero<<<(2 * NG * HID + NG + 255) / 256, 256, 0, stream>>>((int*)PA, 2 * NG * HID + NG);

    k_count<<<(NE + 255) / 256, 256, 0, stream>>>(ei, deg);
    k_scan_part<<<nchunks, 256, 0, stream>>>(deg, part);
    k_scan_top<<<1, 64, 0, stream>>>(part, poff, nchunks);
    k_scan_final<<<nchunks, 256, 0, stream>>>(deg, poff, rowptr, cursor);
    k_fill<<<(NE + 255) / 256, 256, 0, stream>>>(ei, cursor, col);

    k_agg128<<<(NN + 3) / 4, 256, 0, stream>>>(x, agg1, rowptr, col);

    dim3 g1((NN + 63) / 64, HID / 64);
    k_gemm<<<g1, 256, 0, stream>>>(agg1, W1l, x, W1r, b1, h1);

    k_gcnt<<<(NN + 255) / 256, 256, 0, stream>>>(batch, gcnt);
    k_pool<<<(NN + 63) / 64, 256, 0, stream>>>(h1, rowptr, col, batch, PA, PH);

    k_head<<<NG, 256, 0, stream>>>(PA, PH, gcnt, gattr, W2l, b2, W2r, Wf1, bf1, Wf2, bf2v, out);
}

// Round 3
// 694.843 us; speedup vs baseline: 1.5047x; 1.5047x over previous
//
#include <hip/hip_runtime.h>
#include <stdint.h>

#define NN 100000
#define NE 1600000
#define NG 64
#define DIN 128
#define HID 256
#define NATTR 8

typedef unsigned short u16;
typedef __attribute__((ext_vector_type(8))) short s16x8;
typedef __attribute__((ext_vector_type(4))) float f32x4;

__device__ __forceinline__ int imaxi(int a, int b) { return a > b ? a : b; }
__device__ __forceinline__ u16 f2bf(float f) {
    unsigned u = __float_as_uint(f);
    unsigned r = (u + 0x7fffu + ((u >> 16) & 1u)) >> 16;  // RNE
    return (u16)r;
}

// ---------------- zero fill ----------------

__global__ void k_zero(int* __restrict__ p, int n) {
    int i = blockIdx.x * 256 + threadIdx.x;
    if (i < n) p[i] = 0;
}
__global__ void k_zero4(float4* __restrict__ p, int n4) {
    int i = blockIdx.x * 256 + threadIdx.x;
    if (i < n4) p[i] = make_float4(0.f, 0.f, 0.f, 0.f);
}

// ---------------- f32 -> bf16 cast (vector) ----------------

__global__ void k_cast4(const float4* __restrict__ src, ushort4* __restrict__ dst, int n4) {
    int i = blockIdx.x * 256 + threadIdx.x;
    if (i < n4) {
        float4 v = src[i];
        ushort4 o;
        o.x = f2bf(v.x); o.y = f2bf(v.y); o.z = f2bf(v.z); o.w = f2bf(v.w);
        dst[i] = o;
    }
}

// ---------------- weight transpose: W[k][n] f32 -> Wt[n][k] bf16 ----------------

__global__ void k_tw(const float* __restrict__ W1l, const float* __restrict__ W1r,
                     u16* __restrict__ W1lt, u16* __restrict__ W1rt) {
    int i = blockIdx.x * 256 + threadIdx.x;  // 0..65535
    if (i < 32768) {
        int n = i >> 7, k = i & 127;
        W1lt[i] = f2bf(W1l[k * HID + n]);
    } else {
        int j = i - 32768;
        int n = j >> 7, k = j & 127;
        W1rt[j] = f2bf(W1r[k * HID + n]);
    }
}

// ---------------- CSR build ----------------

__global__ void k_count(const int* __restrict__ ei, int* __restrict__ deg) {
    int e = blockIdx.x * 256 + threadIdx.x;
    if (e < NE) atomicAdd(&deg[ei[NE + e]], 1);
}

__global__ void k_scan_part(const int* __restrict__ deg, int* __restrict__ part) {
    __shared__ int red[256];
    int t = threadIdx.x;
    int base = blockIdx.x * 1024 + t * 4;
    int s = 0;
#pragma unroll
    for (int j = 0; j < 4; j++) { int i = base + j; s += (i < NN) ? deg[i] : 0; }
    red[t] = s; __syncthreads();
    for (int off = 128; off > 0; off >>= 1) {
        if (t < off) red[t] += red[t + off];
        __syncthreads();
    }
    if (t == 0) part[blockIdx.x] = red[0];
}

__global__ void k_scan_top(const int* __restrict__ part, int* __restrict__ poff, int nchunks) {
    if (threadIdx.x == 0) {
        int run = 0;
        for (int i = 0; i < nchunks; i++) { poff[i] = run; run += part[i]; }
    }
}

__global__ void k_scan_final(const int* __restrict__ deg, const int* __restrict__ poff,
                             int* __restrict__ rowptr, int* __restrict__ cursor,
                             float* __restrict__ invdeg) {
    __shared__ int arr[256];
    int t = threadIdx.x;
    int base = blockIdx.x * 1024 + t * 4;
    int v[4];
#pragma unroll
    for (int j = 0; j < 4; j++) { int i = base + j; v[j] = (i < NN) ? deg[i] : 0; }
    int T = v[0] + v[1] + v[2] + v[3];
    arr[t] = T; __syncthreads();
    for (int off = 1; off < 256; off <<= 1) {
        int add = (t >= off) ? arr[t - off] : 0;
        __syncthreads();
        arr[t] += add;
        __syncthreads();
    }
    int ex = poff[blockIdx.x] + arr[t] - T;
    int pre = 0;
#pragma unroll
    for (int j = 0; j < 4; j++) {
        int i = base + j;
        int val = ex + pre;
        if (i <= NN) rowptr[i] = val;
        if (i < NN) {
            cursor[i] = val;
            invdeg[i] = 1.0f / (float)imaxi(v[j], 1);
        }
        pre += v[j];
    }
}

__global__ void k_fill(const int* __restrict__ ei, int* __restrict__ cursor, int* __restrict__ col) {
    int e = blockIdx.x * 256 + threadIdx.x;
    if (e < NE) {
        int d = ei[NE + e];
        int p = atomicAdd(&cursor[d], 1);
        col[p] = ei[e];
    }
}

// ---------------- layer-1 mean aggregation (bf16 gather) ----------------
// one wave per node; lane handles 2 bf16 (one dword)

__global__ void k_agg(const u16* __restrict__ xb, u16* __restrict__ agg1,
                      const int* __restrict__ rowptr, const int* __restrict__ col) {
    int node = blockIdx.x * 4 + (threadIdx.x >> 6);
    int lane = threadIdx.x & 63;
    if (node >= NN) return;
    int s = rowptr[node], e = rowptr[node + 1];
    float ax = 0.f, ay = 0.f;
    const unsigned* Xu = (const unsigned*)xb;  // DIN/2 = 64 dwords per row
    for (int i = s; i < e; i++) {
        int u = col[i];
        unsigned w = Xu[(size_t)u * 64 + lane];
        ax += __uint_as_float(w << 16);
        ay += __uint_as_float(w & 0xffff0000u);
    }
    float inv = 1.f / (float)imaxi(e - s, 1);
    unsigned o = (((unsigned)f2bf(ay * inv)) << 16) | (unsigned)f2bf(ax * inv);
    ((unsigned*)agg1)[(size_t)node * 64 + lane] = o;
}

// ---------------- MFMA GEMM1: h1t = relu(agg1@W1l + x@W1r + b1)^T ----------------
// A: [node][k] bf16; B(t): [n][k] bf16; out h1t: [feat][node] bf16. 128x128 tile.

__global__ __launch_bounds__(256) void k_gemm1(
    const u16* __restrict__ agg1, const u16* __restrict__ xb,
    const u16* __restrict__ W1lt, const u16* __restrict__ W1rt,
    const float* __restrict__ b1, u16* __restrict__ h1t) {
    __shared__ u16 As[128][40];
    __shared__ u16 Bs[128][40];
    int t = threadIdx.x;
    int m0 = blockIdx.x * 128;
    int n0 = blockIdx.y * 128;
    int wave = t >> 6, lane = t & 63;
    int wm = wave & 1, wn = wave >> 1;
    int lm = lane & 15, quad = lane >> 4;
    f32x4 acc[4][4] = {};
    const u16* Ap = agg1;
    const u16* Bp = W1lt;
#pragma unroll
    for (int ph = 0; ph < 2; ph++) {
        for (int k0 = 0; k0 < DIN; k0 += 32) {
#pragma unroll
            for (int i = 0; i < 2; i++) {
                int flat = t + i * 256;
                int r = flat >> 2, q = flat & 3;
                int m = m0 + r;
                uint4 v = {0u, 0u, 0u, 0u};
                if (m < NN) v = *(const uint4*)(Ap + (size_t)m * DIN + k0 + q * 8);
                *(uint4*)&As[r][q * 8] = v;
                uint4 w = *(const uint4*)(Bp + (size_t)(n0 + r) * DIN + k0 + q * 8);
                *(uint4*)&Bs[r][q * 8] = w;
            }
            __syncthreads();
            s16x8 af[4], bfr[4];
#pragma unroll
            for (int i = 0; i < 4; i++) {
                af[i]  = *(const s16x8*)&As[wm * 64 + i * 16 + lm][quad * 8];
                bfr[i] = *(const s16x8*)&Bs[wn * 64 + i * 16 + lm][quad * 8];
            }
#pragma unroll
            for (int mi = 0; mi < 4; mi++)
#pragma unroll
                for (int ni = 0; ni < 4; ni++)
                    acc[mi][ni] = __builtin_amdgcn_mfma_f32_16x16x32_bf16(
                        af[mi], bfr[ni], acc[mi][ni], 0, 0, 0);
            __syncthreads();
        }
        Ap = xb; Bp = W1rt;
    }
    // epilogue: C/D layout col=lane&15, row=quad*4+reg -> transposed store (4 rows contiguous)
#pragma unroll
    for (int ni = 0; ni < 4; ni++) {
        int colf = n0 + wn * 64 + ni * 16 + lm;  // feature
        float bias = b1[colf];
#pragma unroll
        for (int mi = 0; mi < 4; mi++) {
            int row = m0 + wm * 64 + mi * 16 + quad * 4;  // node
            if (row < NN) {
                ushort4 o;
                o.x = f2bf(fmaxf(acc[mi][ni][0] + bias, 0.f));
                o.y = f2bf(fmaxf(acc[mi][ni][1] + bias, 0.f));
                o.z = f2bf(fmaxf(acc[mi][ni][2] + bias, 0.f));
                o.w = f2bf(fmaxf(acc[mi][ni][3] + bias, 0.f));
                *(ushort4*)(h1t + (size_t)colf * NN + row) = o;
            }
        }
    }
}

// ---------------- pooled-coefficient matrix build ----------------
// Wbt[g][u]        += invdeg[v] for each edge u->v with batch[v]=g   (rows 0..63)
// Wbt[64+g][v]      = 1                                              (rows 64..127)

__global__ void k_buildw(const int* __restrict__ ei, const int* __restrict__ batch,
                         const float* __restrict__ invdeg, float* __restrict__ Wbt) {
    int e = blockIdx.x * 256 + threadIdx.x;
    if (e < NE) {
        int src = ei[e], dst = ei[NE + e];
        atomicAdd(&Wbt[(size_t)batch[dst] * NN + src], invdeg[dst]);
    }
}

__global__ void k_gcnt(const int* __restrict__ batch, int* __restrict__ gcnt,
                       float* __restrict__ Wbt) {
    __shared__ int lc[NG];
    int t = threadIdx.x;
    if (t < NG) lc[t] = 0;
    __syncthreads();
    int n = blockIdx.x * 256 + t;
    int g = -1;
    if (n < NN) {
        g = batch[n];
        atomicAdd(&lc[g], 1);
        Wbt[(size_t)(NG + g) * NN + n] = 1.0f;
    }
    __syncthreads();
    if (t < NG && lc[t] > 0) atomicAdd(&gcnt[t], lc[t]);
}

// ---------------- pool GEMM (split-K MFMA): P[128][256] = Wbt_bf @ h1t^T ----------------
// A: Wbt_bf [g 128][node], B: h1t [feat][node] (acts as B[k][n] with n=feat via [n][k] storage)

#define KCHUNK 512

__global__ __launch_bounds__(256) void k_poolg(
    const u16* __restrict__ Wbt, const u16* __restrict__ h1t, float* __restrict__ P) {
    __shared__ u16 As[128][40];
    __shared__ u16 Bs[128][40];
    int t = threadIdx.x;
    int kbase = blockIdx.x * KCHUNK;
    int n0 = blockIdx.y * 128;
    int krem = NN - kbase;
    int ksteps = (krem < KCHUNK ? krem : KCHUNK) >> 5;
    int wave = t >> 6, lane = t & 63;
    int wm = wave & 1, wn = wave >> 1;
    int lm = lane & 15, quad = lane >> 4;
    f32x4 acc[4][4] = {};
    for (int ks = 0; ks < ksteps; ks++) {
        int k0 = kbase + ks * 32;
#pragma unroll
        for (int i = 0; i < 2; i++) {
            int flat = t + i * 256;
            int r = flat >> 2, q = flat & 3;
            uint4 v = *(const uint4*)(Wbt + (size_t)r * NN + k0 + q * 8);
            *(uint4*)&As[r][q * 8] = v;
            uint4 w = *(const uint4*)(h1t + (size_t)(n0 + r) * NN + k0 + q * 8);
            *(uint4*)&Bs[r][q * 8] = w;
        }
        __syncthreads();
        s16x8 af[4], bfr[4];
#pragma unroll
        for (int i = 0; i < 4; i++) {
            af[i]  = *(const s16x8*)&As[wm * 64 + i * 16 + lm][quad * 8];
            bfr[i] = *(const s16x8*)&Bs[wn * 64 + i * 16 + lm][quad * 8];
        }
#pragma unroll
        for (int mi = 0; mi < 4; mi++)
#pragma unroll
            for (int ni = 0; ni < 4; ni++)
                acc[mi][ni] = __builtin_amdgcn_mfma_f32_16x16x32_bf16(
                    af[mi], bfr[ni], acc[mi][ni], 0, 0, 0);
        __syncthreads();
    }
#pragma unroll
    for (int mi = 0; mi < 4; mi++)
#pragma unroll
        for (int ni = 0; ni < 4; ni++) {
            int gcol = wm * 64 + mi * 16 + quad * 4;
            int feat = n0 + wn * 64 + ni * 16 + lm;
#pragma unroll
            for (int r = 0; r < 4; r++)
                atomicAdd(&P[(gcol + r) * HID + feat], acc[mi][ni][r]);
        }
}

// ---------------- head: g=(PA@W2l+PH@W2r)/cnt+b2; out=relu([g,attr]@Wf1+bf1)@Wf2+bf2 ----------------

__global__ void k_head(const float* __restrict__ P, const int* __restrict__ gcnt,
                       const float* __restrict__ gattr,
                       const float* __restrict__ W2l, const float* __restrict__ b2,
                       const float* __restrict__ W2r,
                       const float* __restrict__ Wf1, const float* __restrict__ bf1,
                       const float* __restrict__ Wf2, const float* __restrict__ bf2v,
                       float* __restrict__ out) {
    __shared__ float pa[HID], ph[HID], gv[HID + NATTR];
    __shared__ float red[256];
    int g = blockIdx.x, t = threadIdx.x;
    pa[t] = P[g * HID + t];
    ph[t] = P[(NG + g) * HID + t];
    __syncthreads();
    float s = 0.f;
    for (int k = 0; k < HID; k++)
        s += pa[k] * W2l[k * HID + t] + ph[k] * W2r[k * HID + t];
    float invc = 1.f / (float)imaxi(gcnt[g], 1);
    gv[t] = s * invc + b2[t];
    if (t < NATTR) gv[HID + t] = gattr[g * NATTR + t];
    __syncthreads();
    float h = bf1[t];
    for (int k = 0; k < HID + NATTR; k++) h += gv[k] * Wf1[k * HID + t];
    h = fmaxf(h, 0.f);
    red[t] = h * Wf2[t];
    __syncthreads();
    for (int off = 128; off > 0; off >>= 1) {
        if (t < off) red[t] += red[t + off];
        __syncthreads();
    }
    if (t == 0) out[g] = red[0] + bf2v[0];
}

// ---------------- launch ----------------

extern "C" void kernel_launch(void* const* d_in, const int* in_sizes, int n_in,
                              void* d_out, int out_size, void* d_ws, size_t ws_size,
                              hipStream_t stream) {
    (void)in_sizes; (void)n_in; (void)out_size; (void)ws_size;
    const float* x     = (const float*)d_in[0];
    const int*   ei    = (const int*)d_in[1];
    const int*   batch = (const int*)d_in[2];
    const float* gattr = (const float*)d_in[3];
    const float* W1l   = (const float*)d_in[4];
    const float* b1    = (const float*)d_in[5];
    const float* W1r   = (const float*)d_in[6];
    const float* W2l   = (const float*)d_in[7];
    const float* b2    = (const float*)d_in[8];
    const float* W2r   = (const float*)d_in[9];
    const float* Wf1   = (const float*)d_in[10];
    const float* bf1   = (const float*)d_in[11];
    const float* Wf2   = (const float*)d_in[12];
    const float* bf2v  = (const float*)d_in[13];
    float* out = (float*)d_out;

    uint8_t* w = (uint8_t*)d_ws;
    size_t off = 0;
    auto alloc = [&](size_t bytes) -> void* {
        void* p = w + off;
        off += (bytes + 255) & ~(size_t)255;
        return p;
    };
    u16*   xb     = (u16*)alloc((size_t)NN * DIN * 2);        // 25.6 MB
    u16*   agg1   = (u16*)alloc((size_t)NN * DIN * 2);        // 25.6 MB (reused as Wbt_bf)
    u16*   h1t    = (u16*)alloc((size_t)NN * HID * 2);        // 51.2 MB
    float* Wbt_f  = (float*)alloc((size_t)128 * NN * 4);      // 51.2 MB
    u16*   W1lt   = (u16*)alloc((size_t)HID * DIN * 2);
    u16*   W1rt   = (u16*)alloc((size_t)HID * DIN * 2);
    int*   deg    = (int*)alloc((size_t)NN * 4);
    float* invdeg = (float*)alloc((size_t)NN * 4);
    int*   rowptr = (int*)alloc((size_t)(NN + 1) * 4);
    int*   cursor = (int*)alloc((size_t)NN * 4);
    int*   col    = (int*)alloc((size_t)NE * 4);              // 6.4 MB
    int*   part   = (int*)alloc(128 * 4);
    int*   poff   = (int*)alloc(128 * 4);
    float* P      = (float*)alloc((size_t)128 * HID * 4);
    int*   gcnt   = (int*)alloc(NG * 4);
    u16*   Wbt_bf = agg1;  // alias: agg1 dead after k_gemm1, k_cast4(Wbt) runs after

    const int nchunks = (NN + 1023) / 1024;  // 98

    // zeroing
    k_zero4<<<(NN * DIN / 4 + 255) / 256, 256, 0, stream>>>((float4*)Wbt_f, NN * DIN / 4);
    k_zero<<<(NN + 255) / 256, 256, 0, stream>>>(deg, NN);
    k_zero4<<<(128 * HID / 4 + 255) / 256, 256, 0, stream>>>((float4*)P, 128 * HID / 4);
    k_zero<<<1, 64, 0, stream>>>(gcnt, NG);

    // CSR
    k_count<<<(NE + 255) / 256, 256, 0, stream>>>(ei, deg);
    k_scan_part<<<nchunks, 256, 0, stream>>>(deg, part);
    k_scan_top<<<1, 64, 0, stream>>>(part, poff, nchunks);
    k_scan_final<<<nchunks, 256, 0, stream>>>(deg, poff, rowptr, cursor, invdeg);
    k_fill<<<(NE + 255) / 256, 256, 0, stream>>>(ei, cursor, col);

    // casts / transposes / coefficient matrix
    k_cast4<<<(NN * DIN / 4 + 255) / 256, 256, 0, stream>>>((const float4*)x, (ushort4*)xb, NN * DIN / 4);
    k_tw<<<256, 256, 0, stream>>>(W1l, W1r, W1lt, W1rt);
    k_gcnt<<<(NN + 255) / 256, 256, 0, stream>>>(batch, gcnt, Wbt_f);
    k_buildw<<<(NE + 255) / 256, 256, 0, stream>>>(ei, batch, invdeg, Wbt_f);

    // layer 1
    k_agg<<<(NN + 3) / 4, 256, 0, stream>>>(xb, agg1, rowptr, col);
    dim3 g1((NN + 127) / 128, HID / 128);
    k_gemm1<<<g1, 256, 0, stream>>>(agg1, xb, W1lt, W1rt, b1, h1t);

    // pool GEMM (agg1 now dead -> reuse as Wbt_bf)
    k_cast4<<<(128 * NN / 4 + 255) / 256, 256, 0, stream>>>((const float4*)Wbt_f, (ushort4*)Wbt_bf, 128 * NN / 4);
    dim3 g2((NN + KCHUNK - 1) / KCHUNK, HID / 128);
    k_poolg<<<g2, 256, 0, stream>>>(Wbt_bf, h1t, P);

    // head
    k_head<<<NG, 256, 0, stream>>>(P, gcnt, gattr, W2l, b2, W2r, Wf1, bf1, Wf2, bf2v, out);
}